// Round 9
// baseline (203.167 us; speedup 1.0000x reference)
//
#include <hip/hip_runtime.h>

#define HH 512
#define WW 512
#define HW (512*512)
#define NB 8
#define ND 16
#define TW 64            // tile width (output)
#define TH 32            // tile height (output)
#define VR 42            // v-sum rows = TH+10
#define PT 86            // LDS pitch (EVEN -> 8B alignment for all even-col accesses)

__device__ __forceinline__ int reflect(int v) {
    if (v < 0) v = -v;
    if (v >= HH) v = 2*HH - 2 - v;
    return v;
}

// ---------------- Prepass: {mean_I, 1/(var_I+eps)} interleaved float2, per image -------
__global__ __launch_bounds__(256) void img_stats(const float* __restrict__ img,
                                                 float2* __restrict__ miv) {
    const int EE = 42, Q = 43, PH = 33;
    __shared__ float sI[EE*Q], sI2[EE*Q];
    __shared__ float hI[EE*PH], hI2[EE*PH];

    int blk  = blockIdx.x;
    int tile = blk & 255;
    int b    = blk >> 8;
    int ty0  = (tile >> 4) * 32;
    int tx0  = (tile & 15) * 32;
    const float* ib = img + (size_t)b*HW;
    const float inv121 = 1.0f/121.0f;

    for (int i = threadIdx.x; i < EE*EE; i += 256) {
        int y = i / EE, x = i - y*EE;
        int gy = reflect(ty0 - 5 + y);
        int gx = reflect(tx0 - 5 + x);
        float v = ib[gy*WW + gx];
        sI [y*Q + x] = v;
        sI2[y*Q + x] = v*v;
    }
    __syncthreads();
    if (threadIdx.x < 168) {
        int t = threadIdx.x;
        int arr = t / 84, r2 = t - arr*84;
        int seg = r2 / 42, row = r2 - seg*42;
        const float* sr = (arr ? sI2 : sI) + row*Q;
        float* dr = (arr ? hI2 : hI) + row*PH;
        int x0 = seg*16;
        float s = 0.f;
        #pragma unroll
        for (int j = 0; j < 10; ++j) s += sr[x0+j];
        #pragma unroll
        for (int x = 0; x < 16; ++x) {
            s += sr[x0+x+10];
            dr[x0+x] = s;
            s -= sr[x0+x];
        }
    }
    __syncthreads();
    {
        int t = threadIdx.x;
        int arr = t >> 7, r2 = t & 127;
        int seg = r2 >> 5, col = r2 & 31;
        const float* src = arr ? hI2 : hI;
        float* dst = arr ? sI2 : sI;
        int y0 = seg*8;
        float s = 0.f;
        #pragma unroll
        for (int j = 0; j < 10; ++j) s += src[(y0+j)*PH+col];
        #pragma unroll
        for (int k = 0; k < 8; ++k) {
            int y = y0 + k;
            s += src[(y+10)*PH+col];
            dst[y*Q+col] = s;
            s -= src[y*PH+col];
        }
    }
    __syncthreads();
    for (int i = threadIdx.x; i < 32*32; i += 256) {
        int y = i >> 5, x = i & 31;
        float mI  = sI [y*Q+x]*inv121;
        float mII = sI2[y*Q+x]*inv121;
        float var = mII - mI*mI;
        int gy = ty0 + y, gx = tx0 + x;
        float2 o; o.x = mI; o.y = 1.0f / (var + 1e-8f);
        miv[(size_t)b*HW + gy*WW + gx] = o;
    }
}

// ---------------- Main fused kernel: one (b,d) channel, one 64x32 tile -----------------
// Vertical-first. 4 phases, 3 barriers. LDS: hF/hP [42][86] = 28.9 KB.
//   A (252 thr): scalar v-sums of feat & img*feat -> hF/hP raw cols 0..83
//   B (84 thr) : h-sums + a,b inline; in-place col-slots slot(c)=c+10*(c>=38)
//   C (148 thr): v-sums of a,b; in-place row-slots prow(y)=y+10*(y>=16)
//   D (128 thr): h-sums of both arrays + combine + direct global store
__global__ __launch_bounds__(256) void guided_main(const float* __restrict__ feat,
                                                   const float* __restrict__ img,
                                                   const float2* __restrict__ miv,
                                                   float* __restrict__ out) {
    __shared__ __align__(16) float hF[VR*PT];
    __shared__ __align__(16) float hP[VR*PT];

    int blk  = blockIdx.x;
    int tile = blk & 127;        // 8 col-tiles x 16 row-tiles
    int bd   = blk >> 7;
    int b    = bd >> 4;
    int ty0  = (tile >> 3) * TH;
    int tx0  = (tile & 7)  * TW;

    const float inv121 = 1.0f/121.0f;
    const float* fb   = feat + (size_t)bd*HW;
    const float* ib   = img  + (size_t)b*HW;
    const float2* mivb = miv + (size_t)b*HW;
    const int t = threadIdx.x;

    // ---- Phase A: vertical raw 11-sums of feat & img*feat (scalar, coalesced) ----
    // 84 cols x 3 row-segs (14 outputs each) = 252 threads.
    if (t < 252) {
        int seg = t / 84, col = t - seg*84;
        int gx = reflect(tx0 - 10 + col);
        const float* fcol = fb + gx;
        const float* icol = ib + gx;
        int vr0 = seg*14;
        float rf[11], rp[11];
        float sf = 0.f, sp = 0.f;
        #pragma unroll
        for (int j = 0; j < 10; ++j) {
            int gy = reflect(ty0 - 10 + vr0 + j);
            float f = fcol[gy*WW], im = icol[gy*WW];
            float p = f*im;
            rf[j] = f; rp[j] = p; sf += f; sp += p;
        }
        #pragma unroll
        for (int k = 0; k < 14; ++k) {
            int vr = vr0 + k;
            int gy = reflect(ty0 + vr);     // = ty0-10 + (vr+10)
            float f = fcol[gy*WW], im = icol[gy*WW];
            float p = f*im;
            sf += f; sp += p;
            hF[vr*PT + col] = sf;
            hP[vr*PT + col] = sp;
            sf -= rf[k%11]; sp -= rp[k%11];
            rf[(k+10)%11] = f; rp[(k+10)%11] = p;
        }
    }
    __syncthreads();

    // ---- Phase B (fused): h-sums of raw v-sums -> mp,cip -> a,b in place ----
    // 42 rows x 2 col-segs = 84 threads, BOTH arrays per thread.
    // seg0: reads raw 0..47, writes slots 0..37 (trailing). seg1: reads 38..83,
    // writes 48..83 (each b64 word read exactly once, read-before-write same iter).
    if (t < 84) {
        int seg = (t >= 42) ? 1 : 0;
        int vr  = t - seg*42;
        int xb  = seg ? 38 : 0;
        int nout = seg ? 18 : 19;            // pairs
        float* rF = hF + vr*PT;
        float* rP = hP + vr*PT;
        int gy = reflect(ty0 - 5 + vr);
        const float2* mrow = mivb + gy*WW;
        float2 ringF[5], ringP[5];
        float TF = 0.f, TP = 0.f;
        #pragma unroll
        for (int j = 0; j < 5; ++j) {
            float2 vF = *(float2*)(rF + xb + 2*j);
            float2 vP = *(float2*)(rP + xb + 2*j);
            ringF[j] = vF; TF += vF.x + vF.y;
            ringP[j] = vP; TP += vP.x + vP.y;
        }
        #pragma unroll
        for (int k2 = 0; k2 < 19; ++k2) {
            if (k2 < nout) {
                int hc = xb + 2*k2;
                float2 pF = *(float2*)(rF + hc + 10);
                float2 pP = *(float2*)(rP + hc + 10);
                float2 qF = ringF[k2 % 5];
                float2 qP = ringP[k2 % 5];
                float O0f = TF + pF.x;
                float O1f = O0f + pF.y - qF.x;
                TF = O1f - qF.y;
                ringF[k2 % 5] = pF;
                float O0p = TP + pP.x;
                float O1p = O0p + pP.y - qP.x;
                TP = O1p - qP.y;
                ringP[k2 % 5] = pP;
                float mp0  = O0f*inv121, mp1  = O1f*inv121;
                float cip0 = O0p*inv121, cip1 = O1p*inv121;
                int gx0 = tx0 - 5 + hc;
                float2 g0 = mrow[reflect(gx0)];
                float2 g1 = mrow[reflect(gx0+1)];
                float a0 = (cip0 - g0.x*mp0) * g0.y;
                float b0 = mp0 - a0*g0.x;
                float a1 = (cip1 - g1.x*mp1) * g1.y;
                float b1 = mp1 - a1*g1.x;
                float2 oa; oa.x = a0; oa.y = a1;
                float2 ob2; ob2.x = b0; ob2.y = b1;
                *(float2*)(rF + hc + 10*seg) = oa;
                *(float2*)(rP + hc + 10*seg) = ob2;
            }
        }
    }
    __syncthreads();

    // ---- Phase C: vertical 11-sums of a,b; column-pair threads; row-slot in place ----
    // 37 pairs x 2 row-segs x 2 arrays = 148 threads.
    // seg0: reads rows 0..25, writes rows 0..15. seg1: reads 16..41, writes 26..41.
    if (t < 148) {
        int arr = t & 1;
        int j2  = t >> 1;                    // 0..73
        int seg = (j2 >= 37) ? 1 : 0;
        int c2  = j2 - seg*37;
        int x0 = 2*c2;
        int slotc = x0 + ((x0 >= 38) ? 10 : 0);
        int y0 = seg*16;
        float* A = (arr ? hP : hF);
        float2 ring[11];
        float sx = 0.f, sy = 0.f;
        #pragma unroll
        for (int j = 0; j < 10; ++j) {
            float2 v = *(float2*)(A + (y0+j)*PT + slotc);
            ring[j] = v; sx += v.x; sy += v.y;
        }
        #pragma unroll
        for (int k = 0; k < 16; ++k) {
            int y = y0 + k;
            float2 v = *(float2*)(A + (y+10)*PT + slotc);
            sx += v.x; sy += v.y;
            int wrow = y + 10*seg;
            float2 o; o.x = sx; o.y = sy;
            *(float2*)(A + wrow*PT + slotc) = o;
            sx -= ring[k%11].x; sy -= ring[k%11].y;
            ring[(k+10)%11] = v;
        }
    }
    __syncthreads();

    // ---- Phase D (fused): h-sums of summed a,b + combine + direct global store ----
    // 32 rows x 4 col-segs (8 pairs each) = 128 threads, BOTH arrays; reads only in LDS.
    {
        float* ob = out + (size_t)bd*HW;
        if (t < 128) {
            int row = t & 31, seg = t >> 5;   // seg 0..3
            int prow = row + ((row >= 16) ? 10 : 0);
            const float* rA = hF + prow*PT;
            const float* rB = hP + prow*PT;
            int xb = seg*16;
            float2 ringA[5], ringB[5];
            float TA = 0.f, TB = 0.f;
            #pragma unroll
            for (int j = 0; j < 5; ++j) {
                int idx = xb + 2*j;
                int sl = idx + ((idx >= 38) ? 10 : 0);
                float2 vA = *(float2*)(rA + sl);
                float2 vB = *(float2*)(rB + sl);
                ringA[j] = vA; TA += vA.x + vA.y;
                ringB[j] = vB; TB += vB.x + vB.y;
            }
            int gy = ty0 + row;
            const float* irow = ib + gy*WW + tx0;
            float* orow = ob + gy*WW + tx0;
            #pragma unroll
            for (int k2 = 0; k2 < 8; ++k2) {
                int x = xb + 2*k2;
                int idx = x + 10;
                int sl = idx + ((idx >= 38) ? 10 : 0);
                float2 pA = *(float2*)(rA + sl);
                float2 pB = *(float2*)(rB + sl);
                float2 qA = ringA[k2 % 5];
                float2 qB = ringB[k2 % 5];
                float A0 = TA + pA.x;
                float A1 = A0 + pA.y - qA.x;
                TA = A1 - qA.y;
                ringA[k2 % 5] = pA;
                float B0 = TB + pB.x;
                float B1 = B0 + pB.y - qB.x;
                TB = B1 - qB.y;
                ringB[k2 % 5] = pB;
                float2 im2 = *(const float2*)(irow + x);
                float2 o;
                o.x = (A0*im2.x + B0)*inv121;
                o.y = (A1*im2.y + B1)*inv121;
                *(float2*)(orow + x) = o;
            }
        }
    }
}

extern "C" void kernel_launch(void* const* d_in, const int* in_sizes, int n_in,
                              void* d_out, int out_size, void* d_ws, size_t ws_size,
                              hipStream_t stream) {
    const float* feat = (const float*)d_in[0];
    const float* img  = (const float*)d_in[1];
    float* out  = (float*)d_out;
    float2* miv = (float2*)d_ws;             // NB*HW float2 = 16 MiB

    img_stats<<<NB*256, 256, 0, stream>>>(img, miv);
    guided_main<<<NB*ND*128, 256, 0, stream>>>(feat, img, miv, out);
}

// Round 10
// 179.935 us; speedup vs baseline: 1.1291x; 1.1291x over previous
//
#include <hip/hip_runtime.h>

#define HH 512
#define WW 512
#define HW (512*512)
#define NB 8
#define ND 16
#define TW 64            // tile width (output)
#define TH 32            // tile height (output)
#define VR 42            // v-sum rows = TH+10
#define PT 86            // LDS pitch (EVEN -> 8B alignment for all even-col accesses)

__device__ __forceinline__ int reflect(int v) {
    if (v < 0) v = -v;
    if (v >= HH) v = 2*HH - 2 - v;
    return v;
}

// ---------------- Prepass: {mean_I, 1/(var_I+eps)} interleaved float2, per image -------
__global__ __launch_bounds__(256) void img_stats(const float* __restrict__ img,
                                                 float2* __restrict__ miv) {
    const int EE = 42, Q = 43, PH = 33;
    __shared__ float sI[EE*Q], sI2[EE*Q];
    __shared__ float hI[EE*PH], hI2[EE*PH];

    int blk  = blockIdx.x;
    int tile = blk & 255;
    int b    = blk >> 8;
    int ty0  = (tile >> 4) * 32;
    int tx0  = (tile & 15) * 32;
    const float* ib = img + (size_t)b*HW;
    const float inv121 = 1.0f/121.0f;

    for (int i = threadIdx.x; i < EE*EE; i += 256) {
        int y = i / EE, x = i - y*EE;
        int gy = reflect(ty0 - 5 + y);
        int gx = reflect(tx0 - 5 + x);
        float v = ib[gy*WW + gx];
        sI [y*Q + x] = v;
        sI2[y*Q + x] = v*v;
    }
    __syncthreads();
    if (threadIdx.x < 168) {
        int t = threadIdx.x;
        int arr = t / 84, r2 = t - arr*84;
        int seg = r2 / 42, row = r2 - seg*42;
        const float* sr = (arr ? sI2 : sI) + row*Q;
        float* dr = (arr ? hI2 : hI) + row*PH;
        int x0 = seg*16;
        float s = 0.f;
        #pragma unroll
        for (int j = 0; j < 10; ++j) s += sr[x0+j];
        #pragma unroll
        for (int x = 0; x < 16; ++x) {
            s += sr[x0+x+10];
            dr[x0+x] = s;
            s -= sr[x0+x];
        }
    }
    __syncthreads();
    {
        int t = threadIdx.x;
        int arr = t >> 7, r2 = t & 127;
        int seg = r2 >> 5, col = r2 & 31;
        const float* src = arr ? hI2 : hI;
        float* dst = arr ? sI2 : sI;
        int y0 = seg*8;
        float s = 0.f;
        #pragma unroll
        for (int j = 0; j < 10; ++j) s += src[(y0+j)*PH+col];
        #pragma unroll
        for (int k = 0; k < 8; ++k) {
            int y = y0 + k;
            s += src[(y+10)*PH+col];
            dst[y*Q+col] = s;
            s -= src[y*PH+col];
        }
    }
    __syncthreads();
    for (int i = threadIdx.x; i < 32*32; i += 256) {
        int y = i >> 5, x = i & 31;
        float mI  = sI [y*Q+x]*inv121;
        float mII = sI2[y*Q+x]*inv121;
        float var = mII - mI*mI;
        int gy = ty0 + y, gx = tx0 + x;
        float2 o; o.x = mI; o.y = 1.0f / (var + 1e-8f);
        miv[(size_t)b*HW + gy*WW + gx] = o;
    }
}

// ---------------- Main fused kernel: one (b,d) channel, one 64x32 tile -----------------
// Vertical-first. 5 phases, 4 barriers. LDS: hF/hP [42][86] = 28.9 KB.
//   A (252 thr): scalar v-sums of feat & img*feat -> raw cols 0..83
//   B (168 thr): h-sums -> mp,cip (x inv121) in place at col-slots slot(c)=c+10*(c>=38)
//   C (148 thr): FUSED a,b + vertical 11-sums; in-place row-slots prow(y)=y+10*(y>=16)
//   D (128 thr): h-sums of summed a,b; in-place col map wcol(x)=x+20*(x>=32)
//   D2 (256 thr): combine + coalesced float2 store
__global__ __launch_bounds__(256) void guided_main(const float* __restrict__ feat,
                                                   const float* __restrict__ img,
                                                   const float2* __restrict__ miv,
                                                   float* __restrict__ out) {
    __shared__ __align__(16) float hF[VR*PT];
    __shared__ __align__(16) float hP[VR*PT];

    int blk  = blockIdx.x;
    int tile = blk & 127;        // 8 col-tiles x 16 row-tiles
    int bd   = blk >> 7;
    int b    = bd >> 4;
    int ty0  = (tile >> 3) * TH;
    int tx0  = (tile & 7)  * TW;

    const float inv121 = 1.0f/121.0f;
    const float* fb   = feat + (size_t)bd*HW;
    const float* ib   = img  + (size_t)b*HW;
    const float2* mivb = miv + (size_t)b*HW;
    const int t = threadIdx.x;

    // ---- Phase A: vertical raw 11-sums of feat & img*feat (scalar, coalesced) ----
    // 84 cols x 3 row-segs (14 outputs each) = 252 threads.
    if (t < 252) {
        int seg = t / 84, col = t - seg*84;
        int gx = reflect(tx0 - 10 + col);
        const float* fcol = fb + gx;
        const float* icol = ib + gx;
        int vr0 = seg*14;
        float rf[11], rp[11];
        float sf = 0.f, sp = 0.f;
        #pragma unroll
        for (int j = 0; j < 10; ++j) {
            int gy = reflect(ty0 - 10 + vr0 + j);
            float f = fcol[gy*WW], im = icol[gy*WW];
            float p = f*im;
            rf[j] = f; rp[j] = p; sf += f; sp += p;
        }
        #pragma unroll
        for (int k = 0; k < 14; ++k) {
            int vr = vr0 + k;
            int gy = reflect(ty0 + vr);     // = ty0-10 + (vr+10)
            float f = fcol[gy*WW], im = icol[gy*WW];
            float p = f*im;
            sf += f; sp += p;
            hF[vr*PT + col] = sf;
            hP[vr*PT + col] = sp;
            sf -= rf[k%11]; sp -= rp[k%11];
            rf[(k+10)%11] = f; rp[(k+10)%11] = p;
        }
    }
    __syncthreads();

    // ---- Phase B: horizontal 11-sums -> mp/cip (x inv121) in place at col-slots ----
    // 42 rows x 2 segs x 2 arrays = 168 threads; pair outputs via 10-sum trick.
    // seg0: reads raw 0..47, writes 0..37. seg1: reads raw 38..83, writes 48..83
    // (same-addr read-then-write within thread; cross-seg disjoint).
    if (t < 168) {
        int arr = t & 1;
        int j2  = t >> 1;                    // 0..83
        int seg = (j2 >= 42) ? 1 : 0;
        int vr  = j2 - seg*42;
        int xb = seg ? 38 : 0;
        int nout = seg ? 18 : 19;            // pairs
        float* rA = (arr ? hP : hF) + vr*PT;
        float2 ring[5];
        float T = 0.f;
        #pragma unroll
        for (int j = 0; j < 5; ++j) {
            float2 v = *(float2*)(rA + xb + 2*j);
            ring[j] = v; T += v.x + v.y;
        }
        #pragma unroll
        for (int k2 = 0; k2 < 19; ++k2) {
            if (k2 < nout) {
                int hc = xb + 2*k2;
                float2 p = *(float2*)(rA + hc + 10);
                float2 q = ring[k2 % 5];
                float O0 = T + p.x;
                float O1 = O0 + p.y - q.x;
                T = O1 - q.y;
                ring[k2 % 5] = p;
                float2 o; o.x = O0*inv121; o.y = O1*inv121;
                *(float2*)(rA + hc + 10*seg) = o;
            }
        }
    }
    __syncthreads();

    // ---- Phase C (fused a,b): read mp,cip; compute a,b inline; vertical ring; in place ----
    // 37 col-pairs x 2 row-segs x 2 out-arrays = 148 threads.
    // arr=0 lane rings/writes the a-array (hF); arr=1 lane rings/writes b (hP); both
    // lanes read both arrays. Safety: each column-pair is touched ONLY by its adjacent
    // lane pair (same wave -> program order: row r is read at iter r-y0-10, written at
    // iter r-y0). Cross-seg rows disjoint: seg0 writes 0..15 / seg1 reads 16..41;
    // seg1 writes 26..41 / seg0 reads 0..25.
    if (t < 148) {
        int arr = t & 1;
        int j2  = t >> 1;                    // 0..73
        int seg = (j2 >= 37) ? 1 : 0;
        int c2  = j2 - seg*37;
        int x0 = 2*c2;
        int slotc = x0 + ((x0 >= 38) ? 10 : 0);
        int y0 = seg*16;
        int rg0 = reflect(tx0 - 5 + x0);
        int rg1 = reflect(tx0 - 5 + x0 + 1);
        float2 ring[11];
        float sx = 0.f, sy = 0.f;
        #pragma unroll
        for (int j = 0; j < 10; ++j) {
            int y = y0 + j;
            float2 mp2  = *(float2*)(hF + y*PT + slotc);
            float2 cip2 = *(float2*)(hP + y*PT + slotc);
            int gy = reflect(ty0 - 5 + y);
            float2 g0 = mivb[gy*WW + rg0];
            float2 g1 = mivb[gy*WW + rg1];
            float a0 = (cip2.x - g0.x*mp2.x) * g0.y;
            float a1 = (cip2.y - g1.x*mp2.y) * g1.y;
            float2 v;
            v.x = arr ? (mp2.x - a0*g0.x) : a0;
            v.y = arr ? (mp2.y - a1*g1.x) : a1;
            ring[j] = v; sx += v.x; sy += v.y;
        }
        float* A = (arr ? hP : hF);
        #pragma unroll
        for (int k = 0; k < 16; ++k) {
            int y = y0 + k;
            int yr = y + 10;
            float2 mp2  = *(float2*)(hF + yr*PT + slotc);
            float2 cip2 = *(float2*)(hP + yr*PT + slotc);
            int gy = reflect(ty0 - 5 + yr);
            float2 g0 = mivb[gy*WW + rg0];
            float2 g1 = mivb[gy*WW + rg1];
            float a0 = (cip2.x - g0.x*mp2.x) * g0.y;
            float a1 = (cip2.y - g1.x*mp2.y) * g1.y;
            float2 v;
            v.x = arr ? (mp2.x - a0*g0.x) : a0;
            v.y = arr ? (mp2.y - a1*g1.x) : a1;
            sx += v.x; sy += v.y;
            int wrow = y + 10*seg;
            float2 o; o.x = sx; o.y = sy;
            *(float2*)(A + wrow*PT + slotc) = o;
            sx -= ring[k%11].x; sy -= ring[k%11].y;
            ring[(k+10)%11] = v;
        }
    }
    __syncthreads();

    // ---- Phase D: horizontal 11-sums of summed a,b; pair trick; in place ----
    // 32 rows x 2 arrays x 2 col-segs = 128 threads.
    // seg0: reads slots{0..37,48..51}, writes cols 0..31. seg1: reads {32..37,48..83},
    // writes 52..83 (same-addr read-then-write; cross-seg disjoint).
    if (t < 128) {
        int arr = t & 1;
        int r2  = t >> 1;                    // 0..63
        int seg = r2 >> 5, row = r2 & 31;
        int prow = row + ((row >= 16) ? 10 : 0);
        float* rA = (arr ? hP : hF) + prow*PT;
        int xb = seg*32;
        float2 ring[5];
        float T = 0.f;
        #pragma unroll
        for (int j = 0; j < 5; ++j) {
            int idx = xb + 2*j;
            int sl = idx + ((idx >= 38) ? 10 : 0);
            float2 v = *(float2*)(rA + sl);
            ring[j] = v; T += v.x + v.y;
        }
        #pragma unroll
        for (int k2 = 0; k2 < 16; ++k2) {
            int x = xb + 2*k2;
            int idx = x + 10;
            int sl = idx + ((idx >= 38) ? 10 : 0);
            float2 p = *(float2*)(rA + sl);
            float2 q = ring[k2 % 5];
            float O0 = T + p.x;
            float O1 = O0 + p.y - q.x;
            T = O1 - q.y;
            ring[k2 % 5] = p;
            int wcol = x + 20*seg;
            float2 o; o.x = O0; o.y = O1;
            *(float2*)(rA + wcol) = o;
        }
    }
    __syncthreads();

    // ---- Phase D2: combine + coalesced float2 store ----
    float* ob = out + (size_t)bd*HW;
    for (int i = t; i < TH*32; i += 256) {
        int y = i >> 5, c2 = i & 31;
        int x0 = 2*c2;
        int prow = y + ((y >= 16) ? 10 : 0);
        int wcol = (x0 < 32) ? x0 : x0 + 20;
        float2 ma2 = *(float2*)(&hF[prow*PT + wcol]);
        float2 mb2 = *(float2*)(&hP[prow*PT + wcol]);
        int gy = ty0 + y;
        float2 im2 = *(const float2*)(ib + gy*WW + tx0 + x0);
        float2 o;
        o.x = (ma2.x*im2.x + mb2.x)*inv121;
        o.y = (ma2.y*im2.y + mb2.y)*inv121;
        *(float2*)(ob + gy*WW + tx0 + x0) = o;
    }
}

extern "C" void kernel_launch(void* const* d_in, const int* in_sizes, int n_in,
                              void* d_out, int out_size, void* d_ws, size_t ws_size,
                              hipStream_t stream) {
    const float* feat = (const float*)d_in[0];
    const float* img  = (const float*)d_in[1];
    float* out  = (float*)d_out;
    float2* miv = (float2*)d_ws;             // NB*HW float2 = 16 MiB

    img_stats<<<NB*256, 256, 0, stream>>>(img, miv);
    guided_main<<<NB*ND*128, 256, 0, stream>>>(feat, img, miv, out);
}

// Round 11
// 150.655 us; speedup vs baseline: 1.3486x; 1.1944x over previous
//
#include <hip/hip_runtime.h>

#define HH 512
#define WW 512
#define HW (512*512)
#define NB 8
#define ND 16
#define TW 64            // tile width (output)
#define TH 32            // tile height (output)
#define VR 42            // v-sum rows = TH+10
#define PT 86            // LDS pitch (EVEN -> 8B alignment for all even-col accesses)

__device__ __forceinline__ int reflect(int v) {
    if (v < 0) v = -v;
    if (v >= HH) v = 2*HH - 2 - v;
    return v;
}

// ---------------- Prepass: {mean_I, 1/(var_I+eps)} interleaved float2 ----------------
// Mini-R8 structure: 64x32 tiles, vertical-first register rings on (I, I^2),
// float2 h-sum chains with in-place col-slots, coalesced float2 miv store.
__global__ __launch_bounds__(256) void img_stats(const float* __restrict__ img,
                                                 float2* __restrict__ miv) {
    __shared__ __align__(16) float hF[VR*PT];   // v-sums of I
    __shared__ __align__(16) float hP[VR*PT];   // v-sums of I^2

    int blk  = blockIdx.x;
    int tile = blk & 127;        // 8 col-tiles x 16 row-tiles
    int b    = blk >> 7;
    int ty0  = (tile >> 3) * TH;
    int tx0  = (tile & 7)  * TW;

    const float inv121 = 1.0f/121.0f;
    const float* ib = img + (size_t)b*HW;
    const int t = threadIdx.x;

    // ---- Phase A: vertical raw 11-sums of I and I^2 (scalar, coalesced) ----
    if (t < 252) {
        int seg = t / 84, col = t - seg*84;
        int gx = reflect(tx0 - 10 + col);
        const float* icol = ib + gx;
        int vr0 = seg*14;
        float rv[11], rq[11];
        float sv = 0.f, sq = 0.f;
        #pragma unroll
        for (int j = 0; j < 10; ++j) {
            int gy = reflect(ty0 - 10 + vr0 + j);
            float v = icol[gy*WW], q = v*v;
            rv[j] = v; rq[j] = q; sv += v; sq += q;
        }
        #pragma unroll
        for (int k = 0; k < 14; ++k) {
            int vr = vr0 + k;
            int gy = reflect(ty0 + vr);
            float v = icol[gy*WW], q = v*v;
            sv += v; sq += q;
            hF[vr*PT + col] = sv;
            hP[vr*PT + col] = sq;
            sv -= rv[k%11]; sq -= rq[k%11];
            rv[(k+10)%11] = v; rq[(k+10)%11] = q;
        }
    }
    __syncthreads();

    // ---- Phase B: horizontal 11-sums -> meanI/meanII (x inv121) at col-slots ----
    if (t < 168) {
        int arr = t & 1;
        int j2  = t >> 1;                    // 0..83
        int seg = (j2 >= 42) ? 1 : 0;
        int vr  = j2 - seg*42;
        int xb = seg ? 38 : 0;
        int nout = seg ? 18 : 19;            // pairs
        float* rA = (arr ? hP : hF) + vr*PT;
        float2 ring[5];
        float T = 0.f;
        #pragma unroll
        for (int j = 0; j < 5; ++j) {
            float2 v = *(float2*)(rA + xb + 2*j);
            ring[j] = v; T += v.x + v.y;
        }
        #pragma unroll
        for (int k2 = 0; k2 < 19; ++k2) {
            if (k2 < nout) {
                int hc = xb + 2*k2;
                float2 p = *(float2*)(rA + hc + 10);
                float2 q = ring[k2 % 5];
                float O0 = T + p.x;
                float O1 = O0 + p.y - q.x;
                T = O1 - q.y;
                ring[k2 % 5] = p;
                float2 o; o.x = O0*inv121; o.y = O1*inv121;
                *(float2*)(rA + hc + 10*seg) = o;
            }
        }
    }
    __syncthreads();

    // ---- Final: var, 1/(var+eps); coalesced float2 store ----
    float2* mb = miv + (size_t)b*HW;
    for (int i = t; i < TH*TW; i += 256) {
        int y = i >> 6, x = i & 63;
        int vr = y + 5, hc = x + 5;          // tile px -> logical v-row/h-col
        int slot = hc + ((hc >= 38) ? 10 : 0);
        float mI  = hF[vr*PT + slot];
        float mII = hP[vr*PT + slot];
        float var = mII - mI*mI;
        float2 o; o.x = mI; o.y = 1.0f / (var + 1e-8f);
        mb[(ty0 + y)*WW + tx0 + x] = o;
    }
}

// ---------------- Main fused kernel: one (b,d) channel, one 64x32 tile -----------------
// (byte-identical to R8 best-known)
// Vertical-first. Phase A scalar; phases B..D2 float2. LDS: hF/hP [42][86] = 28.9 KB.
//   cols after B : slot(c) = c + 10*(c>=38)    (c in 0..73)
//   rows after C : prow(y) = y + 10*(y>=16)    (y in 0..31)
//   cols after D : wcol(x) = x + 20*(x>=32)    (x in 0..63)
__global__ __launch_bounds__(256) void guided_main(const float* __restrict__ feat,
                                                   const float* __restrict__ img,
                                                   const float2* __restrict__ miv,
                                                   float* __restrict__ out) {
    __shared__ __align__(16) float hF[VR*PT];
    __shared__ __align__(16) float hP[VR*PT];

    int blk  = blockIdx.x;
    int tile = blk & 127;        // 8 col-tiles x 16 row-tiles
    int bd   = blk >> 7;
    int b    = bd >> 4;
    int ty0  = (tile >> 3) * TH;
    int tx0  = (tile & 7)  * TW;

    const float inv121 = 1.0f/121.0f;
    const float* fb   = feat + (size_t)bd*HW;
    const float* ib   = img  + (size_t)b*HW;
    const float2* mivb = miv + (size_t)b*HW;
    const int t = threadIdx.x;

    // ---- Phase A: vertical raw 11-sums of feat & img*feat (scalar, coalesced) ----
    // 84 cols x 3 row-segs (14 outputs each) = 252 threads.
    if (t < 252) {
        int seg = t / 84, col = t - seg*84;
        int gx = reflect(tx0 - 10 + col);
        const float* fcol = fb + gx;
        const float* icol = ib + gx;
        int vr0 = seg*14;
        float rf[11], rp[11];
        float sf = 0.f, sp = 0.f;
        #pragma unroll
        for (int j = 0; j < 10; ++j) {
            int gy = reflect(ty0 - 10 + vr0 + j);
            float f = fcol[gy*WW], im = icol[gy*WW];
            float p = f*im;
            rf[j] = f; rp[j] = p; sf += f; sp += p;
        }
        #pragma unroll
        for (int k = 0; k < 14; ++k) {
            int vr = vr0 + k;
            int gy = reflect(ty0 + vr);     // = ty0-10 + (vr+10)
            float f = fcol[gy*WW], im = icol[gy*WW];
            float p = f*im;
            sf += f; sp += p;
            hF[vr*PT + col] = sf;
            hP[vr*PT + col] = sp;
            sf -= rf[k%11]; sp -= rp[k%11];
            rf[(k+10)%11] = f; rp[(k+10)%11] = p;
        }
    }
    __syncthreads();

    // ---- Phase B: horizontal 11-sums -> mp/cip (x inv121) in place at col-slots ----
    // 42 rows x 2 segs x 2 arrays = 168 threads; pair outputs via 10-sum trick.
    // seg0: reads raw 0..47, writes 0..37. seg1: reads raw 38..83, writes 48..83
    // (same-addr read-then-write within thread; cross-seg disjoint).
    if (t < 168) {
        int arr = t & 1;
        int j2  = t >> 1;                    // 0..83
        int seg = (j2 >= 42) ? 1 : 0;
        int vr  = j2 - seg*42;
        int xb = seg ? 38 : 0;
        int nout = seg ? 18 : 19;            // pairs
        float* rA = (arr ? hP : hF) + vr*PT;
        float2 ring[5];
        float T = 0.f;
        #pragma unroll
        for (int j = 0; j < 5; ++j) {
            float2 v = *(float2*)(rA + xb + 2*j);
            ring[j] = v; T += v.x + v.y;
        }
        #pragma unroll
        for (int k2 = 0; k2 < 19; ++k2) {
            if (k2 < nout) {
                int hc = xb + 2*k2;
                float2 p = *(float2*)(rA + hc + 10);
                float2 q = ring[k2 % 5];
                float O0 = T + p.x;
                float O1 = O0 + p.y - q.x;
                T = O1 - q.y;
                ring[k2 % 5] = p;
                float2 o; o.x = O0*inv121; o.y = O1*inv121;
                *(float2*)(rA + hc + 10*seg) = o;
            }
        }
    }
    __syncthreads();

    // ---- Phase B2: a,b elementwise on pairs; float2 miv loads; in place ----
    for (int i = t; i < VR*37; i += 256) {
        int y = i / 37, c2 = i - y*37;
        int x0 = 2*c2;
        int slot = x0 + ((x0 >= 38) ? 10 : 0);
        float* pF = &hF[y*PT + slot];
        float* pP = &hP[y*PT + slot];
        float2 mp2  = *(float2*)pF;
        float2 cip2 = *(float2*)pP;
        int gy = reflect(ty0 - 5 + y);
        const float2* mrow = mivb + gy*WW;
        int gx0 = tx0 - 5 + x0;
        float2 g0 = mrow[reflect(gx0)];
        float2 g1 = mrow[reflect(gx0+1)];
        float a0 = (cip2.x - g0.x*mp2.x) * g0.y;
        float b0 = mp2.x - a0*g0.x;
        float a1 = (cip2.y - g1.x*mp2.y) * g1.y;
        float b1 = mp2.y - a1*g1.x;
        float2 oa; oa.x = a0; oa.y = a1;
        float2 ob2; ob2.x = b0; ob2.y = b1;
        *(float2*)pF = oa;
        *(float2*)pP = ob2;
    }
    __syncthreads();

    // ---- Phase C: vertical 11-sums of a,b; column-pair threads; row-slot in place ----
    // 37 pairs x 2 row-segs x 2 arrays = 148 threads.
    // seg0: reads rows 0..25, writes rows 0..15. seg1: reads 16..41, writes 26..41.
    if (t < 148) {
        int arr = t & 1;
        int j2  = t >> 1;                    // 0..73
        int seg = (j2 >= 37) ? 1 : 0;
        int c2  = j2 - seg*37;
        int x0 = 2*c2;
        int slotc = x0 + ((x0 >= 38) ? 10 : 0);
        int y0 = seg*16;
        float* A = (arr ? hP : hF);
        float2 ring[11];
        float sx = 0.f, sy = 0.f;
        #pragma unroll
        for (int j = 0; j < 10; ++j) {
            float2 v = *(float2*)(A + (y0+j)*PT + slotc);
            ring[j] = v; sx += v.x; sy += v.y;
        }
        #pragma unroll
        for (int k = 0; k < 16; ++k) {
            int y = y0 + k;
            float2 v = *(float2*)(A + (y+10)*PT + slotc);
            sx += v.x; sy += v.y;
            int wrow = y + 10*seg;
            float2 o; o.x = sx; o.y = sy;
            *(float2*)(A + wrow*PT + slotc) = o;
            sx -= ring[k%11].x; sy -= ring[k%11].y;
            ring[(k+10)%11] = v;
        }
    }
    __syncthreads();

    // ---- Phase D: horizontal 11-sums of summed a,b; pair trick; in place ----
    // 32 rows x 2 arrays x 2 col-segs = 128 threads.
    // seg0: reads slots{0..37,48..51}, writes cols 0..31. seg1: reads {32..37,48..83},
    // writes 52..83 (same-addr read-then-write; cross-seg disjoint).
    if (t < 128) {
        int arr = t & 1;
        int r2  = t >> 1;                    // 0..63
        int seg = r2 >> 5, row = r2 & 31;
        int prow = row + ((row >= 16) ? 10 : 0);
        float* rA = (arr ? hP : hF) + prow*PT;
        int xb = seg*32;
        float2 ring[5];
        float T = 0.f;
        #pragma unroll
        for (int j = 0; j < 5; ++j) {
            int idx = xb + 2*j;
            int sl = idx + ((idx >= 38) ? 10 : 0);
            float2 v = *(float2*)(rA + sl);
            ring[j] = v; T += v.x + v.y;
        }
        #pragma unroll
        for (int k2 = 0; k2 < 16; ++k2) {
            int x = xb + 2*k2;
            int idx = x + 10;
            int sl = idx + ((idx >= 38) ? 10 : 0);
            float2 p = *(float2*)(rA + sl);
            float2 q = ring[k2 % 5];
            float O0 = T + p.x;
            float O1 = O0 + p.y - q.x;
            T = O1 - q.y;
            ring[k2 % 5] = p;
            int wcol = x + 20*seg;
            float2 o; o.x = O0; o.y = O1;
            *(float2*)(rA + wcol) = o;
        }
    }
    __syncthreads();

    // ---- Phase D2: combine + coalesced float2 store ----
    float* ob = out + (size_t)bd*HW;
    for (int i = t; i < TH*32; i += 256) {
        int y = i >> 5, c2 = i & 31;
        int x0 = 2*c2;
        int prow = y + ((y >= 16) ? 10 : 0);
        int wcol = (x0 < 32) ? x0 : x0 + 20;
        float2 ma2 = *(float2*)(&hF[prow*PT + wcol]);
        float2 mb2 = *(float2*)(&hP[prow*PT + wcol]);
        int gy = ty0 + y;
        float2 im2 = *(const float2*)(ib + gy*WW + tx0 + x0);
        float2 o;
        o.x = (ma2.x*im2.x + mb2.x)*inv121;
        o.y = (ma2.y*im2.y + mb2.y)*inv121;
        *(float2*)(ob + gy*WW + tx0 + x0) = o;
    }
}

extern "C" void kernel_launch(void* const* d_in, const int* in_sizes, int n_in,
                              void* d_out, int out_size, void* d_ws, size_t ws_size,
                              hipStream_t stream) {
    const float* feat = (const float*)d_in[0];
    const float* img  = (const float*)d_in[1];
    float* out  = (float*)d_out;
    float2* miv = (float2*)d_ws;             // NB*HW float2 = 16 MiB

    img_stats<<<NB*128, 256, 0, stream>>>(img, miv);
    guided_main<<<NB*ND*128, 256, 0, stream>>>(feat, img, miv, out);
}

// Round 12
// 148.514 us; speedup vs baseline: 1.3680x; 1.0144x over previous
//
#include <hip/hip_runtime.h>

#define HH 512
#define WW 512
#define HW (512*512)
#define NB 8
#define ND 16
#define TW 64            // tile width (output)
#define TH 64            // tile height (output)
#define VR 74            // v-sum rows = TH+10
#define PT 86            // LDS pitch (EVEN -> 8B alignment for all even-col accesses)

__device__ __forceinline__ int reflect(int v) {
    if (v < 0) v = -v;
    if (v >= HH) v = 2*HH - 2 - v;
    return v;
}

// ---------------- Prepass: {mean_I, 1/(var_I+eps)} interleaved float2 ----------------
// (unchanged from R11: 64x32 tiles, vertical-first rings, float2 h-sums)
__global__ __launch_bounds__(256) void img_stats(const float* __restrict__ img,
                                                 float2* __restrict__ miv) {
    const int VRs = 42, PTs = 86, THs = 32, TWs = 64;
    __shared__ __align__(16) float hF[VRs*PTs];
    __shared__ __align__(16) float hP[VRs*PTs];

    int blk  = blockIdx.x;
    int tile = blk & 127;
    int b    = blk >> 7;
    int ty0  = (tile >> 3) * THs;
    int tx0  = (tile & 7)  * TWs;

    const float inv121 = 1.0f/121.0f;
    const float* ib = img + (size_t)b*HW;
    const int t = threadIdx.x;

    if (t < 252) {
        int seg = t / 84, col = t - seg*84;
        int gx = reflect(tx0 - 10 + col);
        const float* icol = ib + gx;
        int vr0 = seg*14;
        float rv[11], rq[11];
        float sv = 0.f, sq = 0.f;
        #pragma unroll
        for (int j = 0; j < 10; ++j) {
            int gy = reflect(ty0 - 10 + vr0 + j);
            float v = icol[gy*WW], q = v*v;
            rv[j] = v; rq[j] = q; sv += v; sq += q;
        }
        #pragma unroll
        for (int k = 0; k < 14; ++k) {
            int vr = vr0 + k;
            int gy = reflect(ty0 + vr);
            float v = icol[gy*WW], q = v*v;
            sv += v; sq += q;
            hF[vr*PTs + col] = sv;
            hP[vr*PTs + col] = sq;
            sv -= rv[k%11]; sq -= rq[k%11];
            rv[(k+10)%11] = v; rq[(k+10)%11] = q;
        }
    }
    __syncthreads();

    if (t < 168) {
        int arr = t & 1;
        int j2  = t >> 1;
        int seg = (j2 >= 42) ? 1 : 0;
        int vr  = j2 - seg*42;
        int xb = seg ? 38 : 0;
        int nout = seg ? 18 : 19;
        float* rA = (arr ? hP : hF) + vr*PTs;
        float2 ring[5];
        float T = 0.f;
        #pragma unroll
        for (int j = 0; j < 5; ++j) {
            float2 v = *(float2*)(rA + xb + 2*j);
            ring[j] = v; T += v.x + v.y;
        }
        #pragma unroll
        for (int k2 = 0; k2 < 19; ++k2) {
            if (k2 < nout) {
                int hc = xb + 2*k2;
                float2 p = *(float2*)(rA + hc + 10);
                float2 q = ring[k2 % 5];
                float O0 = T + p.x;
                float O1 = O0 + p.y - q.x;
                T = O1 - q.y;
                ring[k2 % 5] = p;
                float2 o; o.x = O0*inv121; o.y = O1*inv121;
                *(float2*)(rA + hc + 10*seg) = o;
            }
        }
    }
    __syncthreads();

    float2* mb = miv + (size_t)b*HW;
    for (int i = t; i < THs*TWs; i += 256) {
        int y = i >> 6, x = i & 63;
        int vr = y + 5, hc = x + 5;
        int slot = hc + ((hc >= 38) ? 10 : 0);
        float mI  = hF[vr*PTs + slot];
        float mII = hP[vr*PTs + slot];
        float var = mII - mI*mI;
        float2 o; o.x = mI; o.y = 1.0f / (var + 1e-8f);
        mb[(ty0 + y)*WW + tx0 + x] = o;
    }
}

// ---------------- Main fused kernel: one (b,d) channel, one 64x64 tile, 512 thr --------
// Vertical-first. Phase A scalar; phases B..D2 float2. LDS: hF/hP [74][86] = 50.9 KB
// -> 3 blocks/CU x 8 waves = 24 waves/CU.
//   cols after B : slot(c) = c + 10*(c>=38)    (c in 0..73)
//   rows after C : prow(y) = y + 10*(y>=32)    (y in 0..63)
//   cols after D : wcol(x) = x + 20*(x>=32)    (x in 0..63)
__global__ __launch_bounds__(512) void guided_main(const float* __restrict__ feat,
                                                   const float* __restrict__ img,
                                                   const float2* __restrict__ miv,
                                                   float* __restrict__ out) {
    __shared__ __align__(16) float hF[VR*PT];
    __shared__ __align__(16) float hP[VR*PT];

    int blk  = blockIdx.x;
    int tile = blk & 63;         // 8 col-tiles x 8 row-tiles
    int bd   = blk >> 6;
    int b    = bd >> 4;
    int ty0  = (tile >> 3) * TH;
    int tx0  = (tile & 7)  * TW;

    const float inv121 = 1.0f/121.0f;
    const float* fb   = feat + (size_t)bd*HW;
    const float* ib   = img  + (size_t)b*HW;
    const float2* mivb = miv + (size_t)b*HW;
    const int t = threadIdx.x;

    // ---- Phase A: vertical raw 11-sums of feat & img*feat (scalar, coalesced) ----
    // 84 cols x 6 row-segs (13 outputs each, guard vr<74) = 504 threads.
    if (t < 504) {
        int seg = t / 84, col = t - seg*84;
        int gx = reflect(tx0 - 10 + col);
        const float* fcol = fb + gx;
        const float* icol = ib + gx;
        int vr0 = seg*13;
        float rf[11], rp[11];
        float sf = 0.f, sp = 0.f;
        #pragma unroll
        for (int j = 0; j < 10; ++j) {
            int gy = reflect(ty0 - 10 + vr0 + j);
            float f = fcol[gy*WW], im = icol[gy*WW];
            float p = f*im;
            rf[j] = f; rp[j] = p; sf += f; sp += p;
        }
        #pragma unroll
        for (int k = 0; k < 13; ++k) {
            int vr = vr0 + k;
            if (vr < VR) {
                int gy = reflect(ty0 + vr);     // = ty0-10 + (vr+10)
                float f = fcol[gy*WW], im = icol[gy*WW];
                float p = f*im;
                sf += f; sp += p;
                hF[vr*PT + col] = sf;
                hP[vr*PT + col] = sp;
                sf -= rf[k%11]; sp -= rp[k%11];
                rf[(k+10)%11] = f; rp[(k+10)%11] = p;
            }
        }
    }
    __syncthreads();

    // ---- Phase B: horizontal 11-sums -> mp/cip (x inv121) in place at col-slots ----
    // 74 rows x 2 segs x 2 arrays = 296 threads; pair outputs via 10-sum trick.
    // seg0: reads raw 0..47, writes 0..37. seg1: reads raw 38..83, writes 48..83.
    if (t < 296) {
        int arr = t & 1;
        int j2  = t >> 1;                    // 0..147
        int seg = (j2 >= 74) ? 1 : 0;
        int vr  = j2 - seg*74;
        int xb = seg ? 38 : 0;
        int nout = seg ? 18 : 19;            // pairs
        float* rA = (arr ? hP : hF) + vr*PT;
        float2 ring[5];
        float T = 0.f;
        #pragma unroll
        for (int j = 0; j < 5; ++j) {
            float2 v = *(float2*)(rA + xb + 2*j);
            ring[j] = v; T += v.x + v.y;
        }
        #pragma unroll
        for (int k2 = 0; k2 < 19; ++k2) {
            if (k2 < nout) {
                int hc = xb + 2*k2;
                float2 p = *(float2*)(rA + hc + 10);
                float2 q = ring[k2 % 5];
                float O0 = T + p.x;
                float O1 = O0 + p.y - q.x;
                T = O1 - q.y;
                ring[k2 % 5] = p;
                float2 o; o.x = O0*inv121; o.y = O1*inv121;
                *(float2*)(rA + hc + 10*seg) = o;
            }
        }
    }
    __syncthreads();

    // ---- Phase B2: a,b elementwise on pairs; float2 miv loads; in place ----
    for (int i = t; i < VR*37; i += 512) {
        int y = i / 37, c2 = i - y*37;
        int x0 = 2*c2;
        int slot = x0 + ((x0 >= 38) ? 10 : 0);
        float* pF = &hF[y*PT + slot];
        float* pP = &hP[y*PT + slot];
        float2 mp2  = *(float2*)pF;
        float2 cip2 = *(float2*)pP;
        int gy = reflect(ty0 - 5 + y);
        const float2* mrow = mivb + gy*WW;
        int gx0 = tx0 - 5 + x0;
        float2 g0 = mrow[reflect(gx0)];
        float2 g1 = mrow[reflect(gx0+1)];
        float a0 = (cip2.x - g0.x*mp2.x) * g0.y;
        float b0 = mp2.x - a0*g0.x;
        float a1 = (cip2.y - g1.x*mp2.y) * g1.y;
        float b1 = mp2.y - a1*g1.x;
        float2 oa; oa.x = a0; oa.y = a1;
        float2 ob2; ob2.x = b0; ob2.y = b1;
        *(float2*)pF = oa;
        *(float2*)pP = ob2;
    }
    __syncthreads();

    // ---- Phase C: vertical 11-sums of a,b; column-pair threads; row-slot in place ----
    // 37 pairs x 2 row-segs(32) x 2 arrays = 148 threads.
    // seg0: reads rows 0..41, writes 0..31. seg1: reads 32..73, writes 42..73.
    if (t < 148) {
        int arr = t & 1;
        int j2  = t >> 1;                    // 0..73
        int seg = (j2 >= 37) ? 1 : 0;
        int c2  = j2 - seg*37;
        int x0 = 2*c2;
        int slotc = x0 + ((x0 >= 38) ? 10 : 0);
        int y0 = seg*32;
        float* A = (arr ? hP : hF);
        float2 ring[11];
        float sx = 0.f, sy = 0.f;
        #pragma unroll
        for (int j = 0; j < 10; ++j) {
            float2 v = *(float2*)(A + (y0+j)*PT + slotc);
            ring[j] = v; sx += v.x; sy += v.y;
        }
        #pragma unroll
        for (int k = 0; k < 32; ++k) {
            int y = y0 + k;
            float2 v = *(float2*)(A + (y+10)*PT + slotc);
            sx += v.x; sy += v.y;
            int wrow = y + 10*seg;
            float2 o; o.x = sx; o.y = sy;
            *(float2*)(A + wrow*PT + slotc) = o;
            sx -= ring[k%11].x; sy -= ring[k%11].y;
            ring[(k+10)%11] = v;
        }
    }
    __syncthreads();

    // ---- Phase D: horizontal 11-sums of summed a,b; pair trick; in place ----
    // 64 rows x 2 arrays x 2 col-segs = 256 threads.
    // seg0: reads slots{0..37,48..51}, writes cols 0..31. seg1: reads {32..37,48..83},
    // writes 52..83.
    if (t < 256) {
        int arr = t & 1;
        int r2  = t >> 1;                    // 0..127
        int seg = r2 >> 6, row = r2 & 63;
        int prow = row + ((row >= 32) ? 10 : 0);
        float* rA = (arr ? hP : hF) + prow*PT;
        int xb = seg*32;
        float2 ring[5];
        float T = 0.f;
        #pragma unroll
        for (int j = 0; j < 5; ++j) {
            int idx = xb + 2*j;
            int sl = idx + ((idx >= 38) ? 10 : 0);
            float2 v = *(float2*)(rA + sl);
            ring[j] = v; T += v.x + v.y;
        }
        #pragma unroll
        for (int k2 = 0; k2 < 16; ++k2) {
            int x = xb + 2*k2;
            int idx = x + 10;
            int sl = idx + ((idx >= 38) ? 10 : 0);
            float2 p = *(float2*)(rA + sl);
            float2 q = ring[k2 % 5];
            float O0 = T + p.x;
            float O1 = O0 + p.y - q.x;
            T = O1 - q.y;
            ring[k2 % 5] = p;
            int wcol = x + 20*seg;
            float2 o; o.x = O0; o.y = O1;
            *(float2*)(rA + wcol) = o;
        }
    }
    __syncthreads();

    // ---- Phase D2: combine + coalesced float2 store ----
    float* ob = out + (size_t)bd*HW;
    for (int i = t; i < TH*32; i += 512) {
        int y = i >> 5, c2 = i & 31;
        int x0 = 2*c2;
        int prow = y + ((y >= 32) ? 10 : 0);
        int wcol = (x0 < 32) ? x0 : x0 + 20;
        float2 ma2 = *(float2*)(&hF[prow*PT + wcol]);
        float2 mb2 = *(float2*)(&hP[prow*PT + wcol]);
        int gy = ty0 + y;
        float2 im2 = *(const float2*)(ib + gy*WW + tx0 + x0);
        float2 o;
        o.x = (ma2.x*im2.x + mb2.x)*inv121;
        o.y = (ma2.y*im2.y + mb2.y)*inv121;
        *(float2*)(ob + gy*WW + tx0 + x0) = o;
    }
}

extern "C" void kernel_launch(void* const* d_in, const int* in_sizes, int n_in,
                              void* d_out, int out_size, void* d_ws, size_t ws_size,
                              hipStream_t stream) {
    const float* feat = (const float*)d_in[0];
    const float* img  = (const float*)d_in[1];
    float* out  = (float*)d_out;
    float2* miv = (float2*)d_ws;             // NB*HW float2 = 16 MiB

    img_stats<<<NB*128, 256, 0, stream>>>(img, miv);
    guided_main<<<NB*ND*64, 512, 0, stream>>>(feat, img, miv, out);
}